// Round 1
// baseline (254.382 us; speedup 1.0000x reference)
//
#include <hip/hip_runtime.h>
#include <stdint.h>

typedef float f32x4 __attribute__((ext_vector_type(4)));
typedef __bf16 bf16x8 __attribute__((ext_vector_type(8)));

#define DIM 4608
#define NROWS 16384
#define BK 32
#define NT 16
#define WS_L_BYTES (16 * 4 * 512 * 16)  // 512 KiB per l: 16 steps x [grp4][col512][8 bf16]

// ---------------- prepack: W (fp32) -> ws (bf16, c folded, LDS-tile order) ----------------
__global__ __launch_bounds__(256) void prepack(const float* __restrict__ W0,
                                               const float* __restrict__ W1,
                                               const float* __restrict__ W2,
                                               char* __restrict__ ws) {
  int gid = blockIdx.x * 256 + threadIdx.x;  // 3*16*4*512 = 98304 threads
  int col = gid & 511;
  int rest = gid >> 9;
  int grp = rest & 3;
  rest >>= 2;
  int t = rest & 15;
  int l = rest >> 4;
  const float* W = (l == 0) ? W0 : ((l == 1) ? W1 : W2);
  const float c = 0.044194173824159216f;  // 1/sqrt(512), path normalization folded into W
  union {
    bf16x8 v;
    uint4 u;
  } pk;
#pragma unroll
  for (int jj = 0; jj < 8; ++jj) {
    float v = W[(t * 32 + grp * 8 + jj) * 512 + col] * c;
    pk.v[jj] = (__bf16)v;
  }
  *(uint4*)(ws + (size_t)l * WS_L_BYTES + ((size_t)((t * 4 + grp) * 512 + col) << 4)) = pk.u;
}

// ---------------- per-l GEMM: out[z, OFF + w*D + i] = sum_u Wl[u,w] * x1[z, OFF + u*D + i] ----
// Block: BZ z-samples x all 512 w.  8 waves, wave = 64 w-cols.  K=512 in 16 steps of 32.
template <int D, int BZ, int OFF>
__global__ __launch_bounds__(512) void gemm_l(const float* __restrict__ x1,
                                              const float* __restrict__ x2,
                                              const char* __restrict__ wsl,
                                              float* __restrict__ out) {
  constexpr int BM = BZ * D;            // rows (z,i) per block, multiple of 16
  constexpr int R = BM / 16;            // 16-row tiles
  constexpr int ABYTES = BM * BK * 2;   // bf16 A tile bytes = 4 grp * BM * 16B
  constexpr int CNT = BZ * 8 * D;       // float4 loads per A tile
  constexpr int PF = (CNT + 511) / 512; // loads per thread

  __shared__ __align__(16) char smem[2 * ABYTES + 2 * 32768];

  const int tid = threadIdx.x;
  const int z0 = blockIdx.x * BZ;
  const float* xbase = x1 + (size_t)z0 * DIM + OFF;

  // x2 scale per thread-slot (z fixed per (tid,s) across all steps)
  float px[PF];
#pragma unroll
  for (int s = 0; s < PF; ++s) {
    int idx = tid + s * 512;
    if (idx < CNT) px[s] = x2[z0 + idx / (8 * D)];
  }

  // ---- prologue: stage tile t=0 into buffer 0 ----
  {
#pragma unroll
    for (int s = 0; s < PF; ++s) {
      int idx = tid + s * 512;
      if (idx < CNT) {
        int zl = idx / (8 * D);
        int q = idx - zl * (8 * D);
        f32x4 v = *(const f32x4*)(xbase + (size_t)zl * DIM + q * 4);
#pragma unroll
        for (int e = 0; e < 4; ++e) {
          int cl = q * 4 + e;
          int u = cl / D;
          int i = cl - u * D;
          int r = zl * D + i;
          *(__bf16*)(smem + ((u >> 3) * BM + r) * 16 + (u & 7) * 2) = (__bf16)(v[e] * px[s]);
        }
      }
    }
#pragma unroll
    for (int p = 0; p < 4; ++p) {
      uint4 w = *(const uint4*)(wsl + p * 8192 + tid * 16);
      *(uint4*)(smem + 2 * ABYTES + p * 8192 + tid * 16) = w;
    }
  }

  const int lane = tid & 63;
  const int wave = tid >> 6;
  const int llo = lane & 15;
  const int lhi = lane >> 4;

  f32x4 acc[R][4];
#pragma unroll
  for (int rt = 0; rt < R; ++rt)
#pragma unroll
    for (int ct = 0; ct < 4; ++ct) acc[rt][ct] = (f32x4){0.f, 0.f, 0.f, 0.f};

  int cur = 0;
  for (int t = 0; t < NT; ++t) {
    __syncthreads();  // tile t staged & visible; all waves done reading the other buffer

    // ---- issue prefetch loads for t+1 (hide HBM latency under MFMA) ----
    f32x4 pa[PF];
    uint4 pb[4];
    const bool hasNext = (t < NT - 1);
    if (hasNext) {
      const float* xs = xbase + (t + 1) * BK * D;
#pragma unroll
      for (int s = 0; s < PF; ++s) {
        int idx = tid + s * 512;
        if (idx < CNT) {
          int zl = idx / (8 * D);
          int q = idx - zl * (8 * D);
          pa[s] = *(const f32x4*)(xs + (size_t)zl * DIM + q * 4);
        }
      }
      const char* wt = wsl + (size_t)(t + 1) * 32768;
#pragma unroll
      for (int p = 0; p < 4; ++p) pb[p] = *(const uint4*)(wt + p * 8192 + tid * 16);
    }

    // ---- compute on buffer cur ----
    {
      const char* Al = smem + cur * ABYTES;
      const char* Bl = smem + 2 * ABYTES + cur * 32768;
      bf16x8 bf[4];
#pragma unroll
      for (int ct = 0; ct < 4; ++ct)
        bf[ct] = *(const bf16x8*)(Bl + ((lhi * 512 + wave * 64 + ct * 16 + llo) << 4));
#pragma unroll
      for (int rt = 0; rt < R; ++rt) {
        bf16x8 af = *(const bf16x8*)(Al + ((lhi * BM + rt * 16 + llo) << 4));
#pragma unroll
        for (int ct = 0; ct < 4; ++ct)
          acc[rt][ct] = __builtin_amdgcn_mfma_f32_16x16x32_bf16(af, bf[ct], acc[rt][ct], 0, 0, 0);
      }
    }

    // ---- write prefetched tile into the other buffer ----
    if (hasNext) {
      const int nxt = cur ^ 1;
      char* An = smem + nxt * ABYTES;
      char* Bn = smem + 2 * ABYTES + nxt * 32768;
#pragma unroll
      for (int s = 0; s < PF; ++s) {
        int idx = tid + s * 512;
        if (idx < CNT) {
          int zl = idx / (8 * D);
          int q = idx - zl * (8 * D);
#pragma unroll
          for (int e = 0; e < 4; ++e) {
            int cl = q * 4 + e;
            int u = cl / D;
            int i = cl - u * D;
            int r = zl * D + i;
            *(__bf16*)(An + ((u >> 3) * BM + r) * 16 + (u & 7) * 2) = (__bf16)(pa[s][e] * px[s]);
          }
        }
      }
#pragma unroll
      for (int p = 0; p < 4; ++p) *(uint4*)(Bn + p * 8192 + tid * 16) = pb[p];
      cur = nxt;
    }
  }

  // ---- epilogue: C/D layout col=lane&15, row=(lane>>4)*4+reg ----
  float* obase = out + (size_t)z0 * DIM + OFF;
#pragma unroll
  for (int rt = 0; rt < R; ++rt) {
#pragma unroll
    for (int ct = 0; ct < 4; ++ct) {
      int col = wave * 64 + ct * 16 + llo;
#pragma unroll
      for (int reg = 0; reg < 4; ++reg) {
        int row = rt * 16 + lhi * 4 + reg;
        int z = row / D;
        int i = row - z * D;
        obase[(size_t)z * DIM + col * D + i] = acc[rt][ct][reg];
      }
    }
  }
}

extern "C" void kernel_launch(void* const* d_in, const int* in_sizes, int n_in,
                              void* d_out, int out_size, void* d_ws, size_t ws_size,
                              hipStream_t stream) {
  const float* x1 = (const float*)d_in[0];
  const float* x2 = (const float*)d_in[1];
  const float* W0 = (const float*)d_in[2];
  const float* W1 = (const float*)d_in[3];
  const float* W2 = (const float*)d_in[4];
  float* out = (float*)d_out;
  char* ws = (char*)d_ws;

  prepack<<<384, 256, 0, stream>>>(W0, W1, W2, ws);
  gemm_l<1, 64, 0><<<256, 512, 0, stream>>>(x1, x2, ws, out);
  gemm_l<3, 16, 512><<<1024, 512, 0, stream>>>(x1, x2, ws + WS_L_BYTES, out);
  gemm_l<5, 16, 2048><<<1024, 512, 0, stream>>>(x1, x2, ws + 2 * WS_L_BYTES, out);
}

// Round 2
// 222.628 us; speedup vs baseline: 1.1426x; 1.1426x over previous
//
#include <hip/hip_runtime.h>
#include <stdint.h>

typedef float f32x4 __attribute__((ext_vector_type(4)));
typedef __bf16 bf16x8 __attribute__((ext_vector_type(8)));
typedef unsigned short ushort4v __attribute__((ext_vector_type(4)));

#define DIM 4608
#define BK 32
#define NT 16
#define WS_L_BYTES (16 * 4 * 512 * 16)  // 512 KiB per l: 16 tiles x [grp4][col512][8 bf16]

// ---------------- prepack: W (fp32) -> ws (bf16, c folded, B-fragment order) ----------------
// ws element at ((t*4 + grp)*512 + col)*16 + j*2  holds  c * W[(t*32 + grp*8 + j), col]
// which is exactly the B-fragment byte layout for mfma_f32_16x16x32_bf16:
//   lane (col = lane&15 within ct-tile, kgrp = lane>>4) reads 16B = k-slots kgrp*8..+7.
__global__ __launch_bounds__(256) void prepack(const float* __restrict__ W0,
                                               const float* __restrict__ W1,
                                               const float* __restrict__ W2,
                                               char* __restrict__ ws) {
  int gid = blockIdx.x * 256 + threadIdx.x;  // 3*16*4*512 = 98304 threads
  int col = gid & 511;
  int rest = gid >> 9;
  int grp = rest & 3;
  rest >>= 2;
  int t = rest & 15;
  int l = rest >> 4;
  const float* W = (l == 0) ? W0 : ((l == 1) ? W1 : W2);
  const float c = 0.044194173824159216f;  // 1/sqrt(512) path normalization
  union {
    bf16x8 v;
    uint4 u;
  } pk;
#pragma unroll
  for (int jj = 0; jj < 8; ++jj) {
    float v = W[(t * 32 + grp * 8 + jj) * 512 + col] * c;
    pk.v[jj] = (__bf16)v;
  }
  *(uint4*)(ws + (size_t)l * WS_L_BYTES + ((size_t)((t * 4 + grp) * 512 + col) << 4)) = pk.u;
}

// ---------------- per-l GEMM: out[z, OFF + w*D + i] = x2[z] * sum_u cW[u,w] * x1[z, OFF + u*D + i]
// Block: BZ z-samples x all 512 w. 8 waves; wave = 64 w-cols. K=512 in 16 steps of 32.
// A staged in LDS (double-buffered, fragment order); B fed straight from L2-resident ws
// into registers, prefetched 2 tiles deep. ONE barrier per K-tile.
template <int D, int BZ, int OFF>
__global__ __launch_bounds__(512) void gemm_l(const float* __restrict__ x1,
                                              const float* __restrict__ x2,
                                              const char* __restrict__ wsl,
                                              float* __restrict__ out) {
  constexpr int BM = BZ * D;             // rows (z,i) per block, multiple of 16
  constexpr int R = BM / 16;             // 16-row tiles
  constexpr int ABYTES = BM * BK * 2;    // bf16 A tile bytes
  constexpr int CNT = BZ * 8 * D;        // float4 loads per A tile
  constexpr int PF = (CNT + 511) / 512;  // load slots per thread

  __shared__ __align__(16) char smem[2 * ABYTES];

  const int tid = threadIdx.x;
  const int z0 = blockIdx.x * BZ;
  const float* xbase = x1 + (size_t)z0 * DIM + OFF;

  const int lane = tid & 63;
  const int wave = tid >> 6;
  const int llo = lane & 15;
  const int lhi = lane >> 4;

  f32x4 acc[R][4];
#pragma unroll
  for (int rt = 0; rt < R; ++rt)
#pragma unroll
    for (int ct = 0; ct < 4; ++ct) acc[rt][ct] = (f32x4){0.f, 0.f, 0.f, 0.f};

  // ---- issue global A loads for tile t into pa regs ----
  auto load_a = [&](f32x4 (&pa)[PF], int t) {
    const float* xs = xbase + t * (BK * D);
#pragma unroll
    for (int s = 0; s < PF; ++s) {
      int idx = tid + s * 512;
      if (idx < CNT) {
        int zl = idx / (8 * D);
        int q = idx - zl * (8 * D);
        pa[s] = *(const f32x4*)(xs + (size_t)zl * DIM + q * 4);
      }
    }
  };

  // ---- issue B-fragment loads for tile t straight from ws (L2) ----
  auto load_b = [&](bf16x8 (&b)[4], int t) {
    const char* wt = wsl + (size_t)t * 32768;
#pragma unroll
    for (int ct = 0; ct < 4; ++ct)
      b[ct] = *(const bf16x8*)(wt + ((lhi * 512 + wave * 64 + ct * 16 + llo) << 4));
  };

  // ---- cvt fp32->bf16 and scatter pa into A-buffer (fragment order) ----
  auto stage_write = [&](char* buf, f32x4 (&pa)[PF]) {
#pragma unroll
    for (int s = 0; s < PF; ++s) {
      int idx = tid + s * 512;
      if (idx < CNT) {
        int zl = idx / (8 * D);
        int q = idx - zl * (8 * D);
        if (D == 1) {
          // 4 consecutive u, same row: pack into one 8B LDS write
          int u0 = q * 4;
          union {
            ushort4v us;
            __bf16 b[4];
          } pk;
#pragma unroll
          for (int e = 0; e < 4; ++e) pk.b[e] = (__bf16)pa[s][e];
          *(ushort4v*)(buf + ((u0 >> 3) * BM + zl) * 16 + (u0 & 7) * 2) = pk.us;
        } else {
#pragma unroll
          for (int e = 0; e < 4; ++e) {
            int cl = q * 4 + e;
            int u = cl / D;
            int i = cl - u * D;
            int r = zl * D + i;
            *(__bf16*)(buf + ((u >> 3) * BM + r) * 16 + (u & 7) * 2) = (__bf16)pa[s][e];
          }
        }
      }
    }
  };

  // ---- ds_read A-frags + MFMA against in-reg B ----
  auto compute = [&](const char* buf, bf16x8 (&b)[4]) {
#pragma unroll
    for (int rt = 0; rt < R; ++rt) {
      bf16x8 af = *(const bf16x8*)(buf + ((lhi * BM + rt * 16 + llo) << 4));
#pragma unroll
      for (int ct = 0; ct < 4; ++ct)
        acc[rt][ct] = __builtin_amdgcn_mfma_f32_16x16x32_bf16(af, b[ct], acc[rt][ct], 0, 0, 0);
    }
  };

  // ---- prologue: 2-deep prefetch of A and B ----
  f32x4 paE[PF], paO[PF];
  bf16x8 bE[4], bO[4];
  load_a(paE, 0);
  load_a(paO, 1);
  load_b(bE, 0);
  load_b(bO, 1);

  // ---- main loop: unroll x2 so buffer parity & reg rotation are compile-time ----
  for (int tt = 0; tt < NT / 2; ++tt) {
    const int t = tt * 2;
    // even tile t -> buf0
    stage_write(smem, paE);
    if (t + 2 < NT) load_a(paE, t + 2);  // 2 tiles of slack to cover HBM latency
    __syncthreads();                     // buf0 full; buf1 free (readers of buf1 passed prev barrier)
    compute(smem, bE);
    if (t + 2 < NT) load_b(bE, t + 2);   // WAR after last MFMA use; ~1.5 tiles slack, L2-served
    // odd tile t+1 -> buf1 (no barrier needed: different buffer)
    stage_write(smem + ABYTES, paO);
    if (t + 3 < NT) load_a(paO, t + 3);
    __syncthreads();
    compute(smem + ABYTES, bO);
    if (t + 3 < NT) load_b(bO, t + 3);
  }

  // ---- epilogue: C/D layout col=lane&15, row=(lane>>4)*4+reg; fold x2[z] here ----
  float* obase = out + (size_t)z0 * DIM + OFF;
#pragma unroll
  for (int rt = 0; rt < R; ++rt) {
#pragma unroll
    for (int reg = 0; reg < 4; ++reg) {
      int row = rt * 16 + lhi * 4 + reg;
      int z = row / D;
      int i = row - z * D;
      float s = x2[z0 + z];
#pragma unroll
      for (int ct = 0; ct < 4; ++ct) {
        int col = wave * 64 + ct * 16 + llo;
        obase[(size_t)z * DIM + col * D + i] = acc[rt][ct][reg] * s;
      }
    }
  }
}

extern "C" void kernel_launch(void* const* d_in, const int* in_sizes, int n_in,
                              void* d_out, int out_size, void* d_ws, size_t ws_size,
                              hipStream_t stream) {
  const float* x1 = (const float*)d_in[0];
  const float* x2 = (const float*)d_in[1];
  const float* W0 = (const float*)d_in[2];
  const float* W1 = (const float*)d_in[3];
  const float* W2 = (const float*)d_in[4];
  float* out = (float*)d_out;
  char* ws = (char*)d_ws;

  prepack<<<384, 256, 0, stream>>>(W0, W1, W2, ws);
  gemm_l<1, 64, 0><<<256, 512, 0, stream>>>(x1, x2, ws, out);
  gemm_l<3, 16, 512><<<1024, 512, 0, stream>>>(x1, x2, ws + WS_L_BYTES, out);
  gemm_l<5, 16, 2048><<<1024, 512, 0, stream>>>(x1, x2, ws + 2 * WS_L_BYTES, out);
}

// Round 3
// 218.625 us; speedup vs baseline: 1.1636x; 1.0183x over previous
//
#include <hip/hip_runtime.h>
#include <stdint.h>

typedef float f32x4 __attribute__((ext_vector_type(4)));
typedef __bf16 bf16x8 __attribute__((ext_vector_type(8)));
typedef unsigned short ushort4v __attribute__((ext_vector_type(4)));

#define DIM 4608
#define BK 32
#define NT 16
#define WS_L_BYTES (16 * 4 * 512 * 16)  // 512 KiB per l: 16 tiles x [grp4][col512][8 bf16]

// Phase boundary: pin ds_writes above, wait own LDS ops, raw barrier (NO vmcnt drain —
// this is the whole point: prefetch global loads stay in flight across tiles).
#define BAR()                                    \
  do {                                           \
    __builtin_amdgcn_sched_barrier(0);           \
    asm volatile("s_waitcnt lgkmcnt(0)");        \
    __builtin_amdgcn_s_barrier();                \
    __builtin_amdgcn_sched_barrier(0);           \
  } while (0)

// ---------------- prepack: W (fp32) -> ws (bf16, c folded, B-fragment order) ----------------
__global__ __launch_bounds__(256) void prepack(const float* __restrict__ W0,
                                               const float* __restrict__ W1,
                                               const float* __restrict__ W2,
                                               char* __restrict__ ws) {
  int gid = blockIdx.x * 256 + threadIdx.x;  // 3*16*4*512 = 98304 threads
  int col = gid & 511;
  int rest = gid >> 9;
  int grp = rest & 3;
  rest >>= 2;
  int t = rest & 15;
  int l = rest >> 4;
  const float* W = (l == 0) ? W0 : ((l == 1) ? W1 : W2);
  const float c = 0.044194173824159216f;  // 1/sqrt(512) path normalization
  union {
    bf16x8 v;
    uint4 u;
  } pk;
#pragma unroll
  for (int jj = 0; jj < 8; ++jj) {
    float v = W[(t * 32 + grp * 8 + jj) * 512 + col] * c;
    pk.v[jj] = (__bf16)v;
  }
  *(uint4*)(ws + (size_t)l * WS_L_BYTES + ((size_t)((t * 4 + grp) * 512 + col) << 4)) = pk.u;
}

// ---------------- per-l GEMM: out[z, OFF + w*D + i] = x2[z] * sum_u cW[u,w] * x1[z, OFF + u*D + i]
// Block: BZ z-samples x all 512 w. 8 waves; wave = 64 w-cols. K=512 in 16 tiles of 32.
// A double-buffered in LDS (fragment order); B straight from L2-resident ws into regs.
// Raw-barrier pipeline: global prefetch loads survive barriers (counted vmcnt by compiler).
template <int D, int BZ, int OFF>
__global__ __launch_bounds__(512) void gemm_l(const float* __restrict__ x1,
                                              const float* __restrict__ x2,
                                              const char* __restrict__ wsl,
                                              float* __restrict__ out) {
  constexpr int BM = BZ * D;             // rows (z,i) per block, multiple of 16
  constexpr int R = BM / 16;             // 16-row tiles
  constexpr int ABYTES = BM * BK * 2;    // bf16 A tile bytes
  constexpr int CNT = BZ * 8 * D;        // float4 loads per A tile
  constexpr int PF = (CNT + 511) / 512;  // load slots per thread

  __shared__ __align__(16) char smem[2 * ABYTES];

  const int tid = threadIdx.x;
  const int z0 = blockIdx.x * BZ;
  const float* xbase = x1 + (size_t)z0 * DIM + OFF;

  const int lane = tid & 63;
  const int wave = tid >> 6;
  const int llo = lane & 15;
  const int lhi = lane >> 4;

  f32x4 acc[R][4];
#pragma unroll
  for (int rt = 0; rt < R; ++rt)
#pragma unroll
    for (int ct = 0; ct < 4; ++ct) acc[rt][ct] = (f32x4){0.f, 0.f, 0.f, 0.f};

  auto load_a = [&](f32x4 (&pa)[PF], int t) {
    const float* xs = xbase + t * (BK * D);
#pragma unroll
    for (int s = 0; s < PF; ++s) {
      int idx = tid + s * 512;
      if (idx < CNT) {
        int zl = idx / (8 * D);
        int q = idx - zl * (8 * D);
        pa[s] = *(const f32x4*)(xs + (size_t)zl * DIM + q * 4);
      }
    }
  };

  auto load_b = [&](bf16x8 (&b)[4], int t) {
    const char* wt = wsl + (size_t)t * 32768;
#pragma unroll
    for (int ct = 0; ct < 4; ++ct)
      b[ct] = *(const bf16x8*)(wt + ((lhi * 512 + wave * 64 + ct * 16 + llo) << 4));
  };

  auto stage_write = [&](char* buf, f32x4 (&pa)[PF]) {
#pragma unroll
    for (int s = 0; s < PF; ++s) {
      int idx = tid + s * 512;
      if (idx < CNT) {
        int zl = idx / (8 * D);
        int q = idx - zl * (8 * D);
        if (D == 1) {
          int u0 = q * 4;
          union {
            ushort4v us;
            __bf16 b[4];
          } pk;
#pragma unroll
          for (int e = 0; e < 4; ++e) pk.b[e] = (__bf16)pa[s][e];
          *(ushort4v*)(buf + ((u0 >> 3) * BM + zl) * 16 + (u0 & 7) * 2) = pk.us;
        } else {
#pragma unroll
          for (int e = 0; e < 4; ++e) {
            int cl = q * 4 + e;
            int u = cl / D;
            int i = cl - u * D;
            int r = zl * D + i;
            *(__bf16*)(buf + ((u >> 3) * BM + r) * 16 + (u & 7) * 2) = (__bf16)pa[s][e];
          }
        }
      }
    }
  };

  auto compute = [&](const char* buf, bf16x8 (&b)[4]) {
#pragma unroll
    for (int rt = 0; rt < R; ++rt) {
      bf16x8 af = *(const bf16x8*)(buf + ((lhi * BM + rt * 16 + llo) << 4));
#pragma unroll
      for (int ct = 0; ct < 4; ++ct)
        acc[rt][ct] = __builtin_amdgcn_mfma_f32_16x16x32_bf16(af, b[ct], acc[rt][ct], 0, 0, 0);
    }
  };

  // ---- prologue: 2-deep prefetch; stage tile 0 ----
  f32x4 paE[PF], paO[PF];
  bf16x8 bE[4], bO[4];
  load_a(paE, 0);
  load_b(bE, 0);
  load_a(paO, 1);
  load_b(bO, 1);
  stage_write(smem, paE);  // waits only paE(0) loads (counted vmcnt)
  load_a(paE, 2);
  BAR();

  // ---- main loop: fully unrolled, E/O register parity compile-time ----
#pragma unroll
  for (int tt = 0; tt < NT / 2; ++tt) {
    const int t = 2 * tt;
    // phase E: compute tile t from buf0; stage tile t+1 into buf1
    compute(smem, bE);
    if (t + 2 < NT) load_b(bE, t + 2);
    stage_write(smem + ABYTES, paO);  // waits paO(t+1); paE(t+2)/bE(t+2) stay in flight
    if (t + 3 < NT) load_a(paO, t + 3);
    BAR();
    // phase O: compute tile t+1 from buf1; stage tile t+2 into buf0
    compute(smem + ABYTES, bO);
    if (t + 3 < NT) load_b(bO, t + 3);
    if (t + 2 < NT) {
      stage_write(smem, paE);  // paE holds tile t+2
      if (t + 4 < NT) load_a(paE, t + 4);
      BAR();
    }
  }

  // ---- epilogue: C/D layout col=lane&15, row=(lane>>4)*4+reg; fold x2[z] here ----
  float* obase = out + (size_t)z0 * DIM + OFF;
#pragma unroll
  for (int rt = 0; rt < R; ++rt) {
#pragma unroll
    for (int reg = 0; reg < 4; ++reg) {
      int row = rt * 16 + lhi * 4 + reg;
      int z = row / D;
      int i = row - z * D;
      float s = x2[z0 + z];
#pragma unroll
      for (int ct = 0; ct < 4; ++ct) {
        int col = wave * 64 + ct * 16 + llo;
        obase[(size_t)z * DIM + col * D + i] = acc[rt][ct][reg] * s;
      }
    }
  }
}

extern "C" void kernel_launch(void* const* d_in, const int* in_sizes, int n_in,
                              void* d_out, int out_size, void* d_ws, size_t ws_size,
                              hipStream_t stream) {
  const float* x1 = (const float*)d_in[0];
  const float* x2 = (const float*)d_in[1];
  const float* W0 = (const float*)d_in[2];
  const float* W1 = (const float*)d_in[3];
  const float* W2 = (const float*)d_in[4];
  float* out = (float*)d_out;
  char* ws = (char*)d_ws;

  prepack<<<384, 256, 0, stream>>>(W0, W1, W2, ws);
  gemm_l<1, 64, 0><<<256, 512, 0, stream>>>(x1, x2, ws, out);
  gemm_l<3, 16, 512><<<1024, 512, 0, stream>>>(x1, x2, ws + WS_L_BYTES, out);
  gemm_l<5, 16, 2048><<<1024, 512, 0, stream>>>(x1, x2, ws + 2 * WS_L_BYTES, out);
}